// Round 2
// baseline (10294.472 us; speedup 1.0000x reference)
//
#include <hip/hip_runtime.h>
#include <hip/hip_cooperative_groups.h>
#include <stdint.h>

namespace cg = cooperative_groups;

typedef unsigned short us;
typedef __attribute__((ext_vector_type(8))) short bf16x8;
typedef __attribute__((ext_vector_type(4))) float f32x4;

#define DI __device__ __forceinline__

constexpr int LS = 48, LT = 48, NB = 64, E = 512, G = 2048, V = 32000;
constexpr int TD = LT - 1;       // 47 decoder steps
constexpr int MENC = LS * NB;    // 3072
constexpr int MDEC = TD * NB;    // 3008
constexpr int NCB = V / 64;      // 500 column blocks for logits stats

DI float bf2f(us u) { union { unsigned int i; float f; } c; c.i = ((unsigned int)u) << 16; return c.f; }
DI us f2bf(float f) { union { float f; unsigned int i; } c; c.f = f; return (us)((c.i + 0x7fffu + ((c.i >> 16) & 1u)) >> 16); }
DI float sigm(float x) { return 1.f / (1.f + __expf(-x)); }
DI float tanh_(float x) { x = fminf(15.f, fmaxf(-15.f, x)); float e = __expf(2.f * x); return (e - 1.f) / (e + 1.f); }

// ---------------- utility kernels ----------------
__global__ __launch_bounds__(256) void zero_k(float* p, int n) {
    int i = blockIdx.x * 256 + threadIdx.x;
    if (i < n) p[i] = 0.f;
}

__global__ __launch_bounds__(256) void conv_bf16(const float* __restrict__ src, int lds, int coff,
                                                 us* __restrict__ dst, int rows, int cols) {
    int i = blockIdx.x * 256 + threadIdx.x;
    if (i >= rows * cols) return;
    int r = i / cols, c = i % cols;
    dst[i] = f2bf(src[(size_t)r * lds + coff + c]);
}

__global__ __launch_bounds__(256) void gather_bf16(const int* __restrict__ idx, const float* __restrict__ emb,
                                                   us* __restrict__ dst) {
    int r = blockIdx.x;
    int id = idx[r];
    const float* s = emb + (size_t)id * E;
    us* d = dst + (size_t)r * E;
    for (int c = threadIdx.x; c < E; c += 256) d[c] = f2bf(s[c]);
}

__global__ __launch_bounds__(256) void pack_wcomb(const float* __restrict__ Wih, const float* __restrict__ Whh,
                                                  float* __restrict__ Wc) {
    int i = blockIdx.x * 256 + threadIdx.x;  // 2048*1024
    int j = i >> 10, c = i & 1023;
    Wc[i] = (c < 512) ? Wih[(size_t)j * 1024 + 512 + c] : Whh[(size_t)j * 512 + (c - 512)];
}

// ---------------- bf16 MFMA GEMM: C[M][N] = A[M][K] @ W[N][K]^T (+bias) ----------------
template <int EPI>
__global__ __launch_bounds__(256) void gemm16(const us* __restrict__ A, int lda,
                                              const us* __restrict__ W, int ldw,
                                              const float* __restrict__ b1, const float* __restrict__ b2,
                                              void* __restrict__ outp, int ldc, int K, int Mrows) {
    __shared__ us As[64][40];
    __shared__ us Ws[64][40];
    const int tid = threadIdx.x;
    const int m0 = blockIdx.y << 6, n0 = blockIdx.x << 6;
    const int srow = tid >> 2, sk = (tid & 3) << 3;
    const int l = tid & 63, w = tid >> 6;
    const int la = l & 15, lb = l >> 4;
    f32x4 acc[4] = {};
    const us* Aptr = A + (size_t)(m0 + srow) * lda + sk;
    const us* Wptr = W + (size_t)(n0 + srow) * ldw + sk;
    for (int k0 = 0; k0 < K; k0 += 32) {
        *(uint4*)&As[srow][sk] = *(const uint4*)(Aptr + k0);
        *(uint4*)&Ws[srow][sk] = *(const uint4*)(Wptr + k0);
        __syncthreads();
        bf16x8 af = *(bf16x8*)&As[(w << 4) + la][lb << 3];
#pragma unroll
        for (int c = 0; c < 4; c++) {
            bf16x8 bw = *(bf16x8*)&Ws[(c << 4) + la][lb << 3];
            acc[c] = __builtin_amdgcn_mfma_f32_16x16x32_bf16(af, bw, acc[c], 0, 0, 0);
        }
        __syncthreads();
    }
    if (EPI == 1) {
        us* O = (us*)outp;
#pragma unroll
        for (int c = 0; c < 4; c++) {
            int col = n0 + (c << 4) + la;
            float badd = (b1 ? b1[col] : 0.f) + (b2 ? b2[col] : 0.f);
#pragma unroll
            for (int r = 0; r < 4; r++) {
                int row = m0 + (w << 4) + (lb << 2) + r;
                O[(size_t)row * ldc + col] = f2bf(acc[c][r] + badd);
            }
        }
    } else {
        float* S = (float*)outp;
        float x[4][4];
#pragma unroll
        for (int c = 0; c < 4; c++) {
            int col = n0 + (c << 4) + la;
            float badd = b1[col];
#pragma unroll
            for (int r = 0; r < 4; r++) x[c][r] = acc[c][r] + badd;
        }
#pragma unroll
        for (int r = 0; r < 4; r++) {
            float lm = fmaxf(fmaxf(x[0][r], x[1][r]), fmaxf(x[2][r], x[3][r]));
#pragma unroll
            for (int mk = 1; mk < 16; mk <<= 1) lm = fmaxf(lm, __shfl_xor(lm, mk));
            float ls = __expf(x[0][r] - lm) + __expf(x[1][r] - lm) + __expf(x[2][r] - lm) + __expf(x[3][r] - lm);
#pragma unroll
            for (int mk = 1; mk < 16; mk <<= 1) ls += __shfl_xor(ls, mk);
            if (la == 0) {
                int row = m0 + (w << 4) + (lb << 2) + r;
                size_t o = ((size_t)blockIdx.x * Mrows + row) * 2;
                S[o] = lm;
                S[o + 1] = ls;
            }
        }
    }
}

// ---------------- persistent cooperative encoder: all 48 steps, both dirs ----------------
// grid 256 blocks x 256 thr. block = jt(0..31) | btile(0..3) | dir(0..1). thread = bl(16) x jl(16).
__global__ __launch_bounds__(256) void enc_coop(const us* __restrict__ gxf, const us* __restrict__ gxb,
                                                const float* __restrict__ Whhf, const float* __restrict__ Whhb,
                                                float* __restrict__ hA, float* __restrict__ hB,
                                                us* __restrict__ hs_bf) {
    cg::grid_group gg = cg::this_grid();
    const int bx = blockIdx.x;
    const int jt = bx & 31, btile = (bx >> 5) & 3, dir = bx >> 7;
    const us* gx = dir ? gxb : gxf;
    const float* Whh = dir ? Whhb : Whhf;
    const int tid = threadIdx.x, bl = tid & 15, jl = tid >> 4;
    const int b0 = btile * 16, b = b0 + bl, j = jt * 16 + jl;
    __shared__ float hls[16][516];
    float cstate = 0.f;
    const float* wi = Whh + (size_t)j * 512;
    const float* wf = Whh + (size_t)(512 + j) * 512;
    const float* wg = Whh + (size_t)(1024 + j) * 512;
    const float* wo = Whh + (size_t)(1536 + j) * 512;
    const size_t dof = (size_t)dir * NB * 512;
    for (int s = 0; s < LS; ++s) {
        const float* hin = ((s & 1) ? hB : hA) + dof;
        float* hout = ((s & 1) ? hA : hB) + dof;
        const int lrow = dir ? (LS - 1 - s) : s;
        for (int idx = tid; idx < 16 * 512; idx += 256) {
            int r = idx >> 9, c = idx & 511;
            hls[r][c] = hin[(size_t)(b0 + r) * 512 + c];
        }
        __syncthreads();
        const us* grow = gx + ((size_t)lrow * NB + b) * G;
        float ai = bf2f(grow[j]), af = bf2f(grow[512 + j]), ag = bf2f(grow[1024 + j]), ao = bf2f(grow[1536 + j]);
        for (int k = 0; k < 512; k += 4) {
            float4 h4 = *(float4*)&hls[bl][k];
            float4 a = *(const float4*)&wi[k]; ai += a.x * h4.x + a.y * h4.y + a.z * h4.z + a.w * h4.w;
            float4 f = *(const float4*)&wf[k]; af += f.x * h4.x + f.y * h4.y + f.z * h4.z + f.w * h4.w;
            float4 g = *(const float4*)&wg[k]; ag += g.x * h4.x + g.y * h4.y + g.z * h4.z + g.w * h4.w;
            float4 o = *(const float4*)&wo[k]; ao += o.x * h4.x + o.y * h4.y + o.z * h4.z + o.w * h4.w;
        }
        float cn = sigm(af) * cstate + sigm(ai) * tanh_(ag);
        float hn = sigm(ao) * tanh_(cn);
        cstate = cn;
        hout[(size_t)b * 512 + j] = hn;
        hs_bf[((size_t)lrow * NB + b) * 1024 + dir * 512 + j] = f2bf(hn);
        gg.sync();
    }
}

// ---------------- persistent cooperative decoder: 47 steps, 3 phases/step ----------------
// grid 256 blocks x 256 thr.
__global__ __launch_bounds__(256) void dec_coop(const us* __restrict__ gemb, const float* __restrict__ Wcomb,
                                                const float* __restrict__ attn_W, const float* __restrict__ attn_v,
                                                const us* __restrict__ hsproj, const us* __restrict__ hs_bf,
                                                const us* __restrict__ linw_bf, const float* __restrict__ lin_b,
                                                float* __restrict__ h0, float* __restrict__ h1,
                                                float* __restrict__ od, float* __restrict__ qbuf,
                                                us* __restrict__ hdec_bf) {
    cg::grid_group gg = cg::this_grid();
    const int tid = threadIdx.x;
    const int bx = blockIdx.x;
    __shared__ float uls[8][1044];   // phase A/B staging (1044: 8*1044 mod-32 spread)
    __shared__ float u2ls[1544];     // phase C: [c(1024); h(512)]
    __shared__ float sls[48], pls[48];

    // phase A ids: kh(1) | bl(3) | jl(4)
    const int khA = tid & 1, blA = (tid >> 1) & 7, jlA = tid >> 4;
    const int bgrp = bx >> 5, jt = bx & 31;
    const int bA = bgrp * 8 + blA, jA = jt * 16 + jlA;
    // phase B ids
    const int blB = tid & 7, nlB = tid >> 3;
    const int bB = bgrp * 8 + blB, nB = jt * 32 + nlB;
    // phase C ids
    const int bC = bx >> 2, qtr = bx & 3;
    const int wC = tid >> 6, lC = tid & 63;

    float cstate = 0.f;
    const float* wiA = Wcomb + ((size_t)jA) * 1024 + khA * 512;
    const float* wfA = Wcomb + ((size_t)(512 + jA)) * 1024 + khA * 512;
    const float* wgA = Wcomb + ((size_t)(1024 + jA)) * 1024 + khA * 512;
    const float* woA = Wcomb + ((size_t)(1536 + jA)) * 1024 + khA * 512;

    float vv[16];
#pragma unroll
    for (int i = 0; i < 16; i++) vv[i] = attn_v[lC * 16 + i];

    for (int t = 0; t < TD; ++t) {
        const float* hprev = (t & 1) ? h1 : h0;
        float* hnext = (t & 1) ? h0 : h1;
        // ---- phase A: LSTM cell (split-K x2 per cell) ----
        {
            const int b0 = bgrp * 8;
            for (int idx = tid; idx < 8 * 1024; idx += 256) {
                int r = idx >> 10, c = idx & 1023;
                uls[r][c] = (c < 512) ? od[(size_t)(b0 + r) * 512 + c]
                                      : hprev[(size_t)(b0 + r) * 512 + (c - 512)];
            }
            __syncthreads();
            float ai = 0.f, af = 0.f, ag = 0.f, ao = 0.f;
            const float* u = &uls[blA][khA * 512];
            for (int k = 0; k < 512; k += 4) {
                float4 h4 = *(float4*)&u[k];
                float4 a = *(const float4*)&wiA[k]; ai += a.x * h4.x + a.y * h4.y + a.z * h4.z + a.w * h4.w;
                float4 f = *(const float4*)&wfA[k]; af += f.x * h4.x + f.y * h4.y + f.z * h4.z + f.w * h4.w;
                float4 g = *(const float4*)&wgA[k]; ag += g.x * h4.x + g.y * h4.y + g.z * h4.z + g.w * h4.w;
                float4 o = *(const float4*)&woA[k]; ao += o.x * h4.x + o.y * h4.y + o.z * h4.z + o.w * h4.w;
            }
            ai += __shfl_xor(ai, 1); af += __shfl_xor(af, 1);
            ag += __shfl_xor(ag, 1); ao += __shfl_xor(ao, 1);
            if (khA == 0) {
                const us* grow = gemb + ((size_t)t * NB + bA) * G;
                ai += bf2f(grow[jA]); af += bf2f(grow[512 + jA]);
                ag += bf2f(grow[1024 + jA]); ao += bf2f(grow[1536 + jA]);
                float cn = sigm(af) * cstate + sigm(ai) * tanh_(ag);
                float hn = sigm(ao) * tanh_(cn);
                cstate = cn;
                hnext[(size_t)bA * 512 + jA] = hn;
                hdec_bf[((size_t)t * NB + bA) * 512 + jA] = f2bf(hn);
            }
        }
        gg.sync();
        // ---- phase B: q = h @ Wq^T (distributed) ----
        if (t < TD - 1) {
            for (int idx = tid; idx < 8 * 512; idx += 256) {
                int r = idx >> 9, c = idx & 511;
                uls[r][c] = hnext[(size_t)(bgrp * 8 + r) * 512 + c];
            }
            __syncthreads();
            const float* wq = attn_W + (size_t)nB * 1536;
            const float* u = &uls[blB][0];
            float acc = 0.f;
            for (int k = 0; k < 512; k += 4) {
                float4 h4 = *(float4*)&u[k];
                float4 wv = *(const float4*)&wq[k];
                acc += h4.x * wv.x + h4.y * wv.y + h4.z * wv.z + h4.w * wv.w;
            }
            qbuf[(size_t)bB * 1024 + nB] = acc;
        }
        gg.sync();
        // ---- phase C: scores + softmax + context + o (per (b, quarter)) ----
        if (t < TD - 1) {
            float qv[16];
#pragma unroll
            for (int i = 0; i < 16; i++) qv[i] = qbuf[(size_t)bC * 1024 + lC * 16 + i];
            for (int c = tid; c < 512; c += 256) u2ls[1024 + c] = hnext[(size_t)bC * 512 + c];
            // scores (each wave: 12 rows)
            for (int li = wC * 12; li < wC * 12 + 12; ++li) {
                const us* hp = hsproj + ((size_t)li * NB + bC) * 1024 + lC * 16;
                float p = 0.f;
#pragma unroll
                for (int i = 0; i < 16; i++) p += vv[i] * tanh_(bf2f(hp[i]) + qv[i]);
#pragma unroll
                for (int m = 1; m < 64; m <<= 1) p += __shfl_xor(p, m);
                if (lC == 0) sls[li] = p;
            }
            __syncthreads();
            if (wC == 0) {
                float x = (lC < 48) ? sls[lC] : -1e30f;
                float mx = x;
#pragma unroll
                for (int m = 1; m < 64; m <<= 1) mx = fmaxf(mx, __shfl_xor(mx, m));
                float e = (lC < 48) ? __expf(x - mx) : 0.f;
                float s = e;
#pragma unroll
                for (int m = 1; m < 64; m <<= 1) s += __shfl_xor(s, m);
                if (lC < 48) pls[lC] = e / s;
            }
            __syncthreads();
            {   // context -> u2ls[0..1024)
                int d0 = tid * 4;
                float a0 = 0, a1 = 0, a2 = 0, a3 = 0;
                for (int li = 0; li < 48; ++li) {
                    float pw = pls[li];
                    const us* hv = hs_bf + ((size_t)li * NB + bC) * 1024 + d0;
                    a0 += pw * bf2f(hv[0]); a1 += pw * bf2f(hv[1]);
                    a2 += pw * bf2f(hv[2]); a3 += pw * bf2f(hv[3]);
                }
                u2ls[d0] = a0; u2ls[d0 + 1] = a1; u2ls[d0 + 2] = a2; u2ls[d0 + 3] = a3;
            }
            __syncthreads();
            {   // o slice: 128 dims per quarter, split-K x2
                int d = qtr * 128 + (tid >> 1);
                int kh2 = tid & 1;
                const us* wr = linw_bf + (size_t)d * 1536 + kh2 * 768;
                const float* u2 = &u2ls[kh2 * 768];
                float acc = 0.f;
                for (int k = 0; k < 768; k += 8) {
                    float4 ua = *(const float4*)&u2[k];
                    float4 ub = *(const float4*)&u2[k + 4];
                    acc += bf2f(wr[k]) * ua.x + bf2f(wr[k + 1]) * ua.y + bf2f(wr[k + 2]) * ua.z + bf2f(wr[k + 3]) * ua.w;
                    acc += bf2f(wr[k + 4]) * ub.x + bf2f(wr[k + 5]) * ub.y + bf2f(wr[k + 6]) * ub.z + bf2f(wr[k + 7]) * ub.w;
                }
                acc += __shfl_xor(acc, 1);
                if (kh2 == 0) od[(size_t)bC * 512 + d] = tanh_(acc + lin_b[d]);
            }
        }
        gg.sync();
    }
}

// ---------------- target logit: one wave per (t,b) row ----------------
__global__ __launch_bounds__(256) void tgt_kernel(const us* __restrict__ hdec_bf, const us* __restrict__ woutbf,
                                                  const float* __restrict__ out_b, const int* __restrict__ ts,
                                                  float* __restrict__ tgt) {
    int wid = blockIdx.x * 4 + (threadIdx.x >> 6);
    int l = threadIdx.x & 63;
    int t = wid >> 6, b = wid & 63;
    int tg = ts[(t + 1) * NB + b];
    const us* hr = hdec_bf + (size_t)wid * 512 + l * 8;
    const us* wr = woutbf + (size_t)tg * 512 + l * 8;
    float acc = 0.f;
#pragma unroll
    for (int i = 0; i < 8; i++) acc += bf2f(hr[i]) * bf2f(wr[i]);
#pragma unroll
    for (int m = 1; m < 64; m <<= 1) acc += __shfl_xor(acc, m);
    if (l == 0) tgt[wid] = acc + out_b[tg];
}

__global__ __launch_bounds__(256) void stats_reduce(const float* __restrict__ stats, const float* __restrict__ tgt,
                                                    const int* __restrict__ ts, float* __restrict__ sums) {
    int r = blockIdx.x * 256 + threadIdx.x;
    float nll = 0.f, mk = 0.f;
    if (r < MDEC) {
        float M = -1e30f, S = 0.f;
        for (int cb = 0; cb < NCB; ++cb) {
            float m = stats[((size_t)cb * MDEC + r) * 2];
            float s = stats[((size_t)cb * MDEC + r) * 2 + 1];
            if (m > M) { S = S * __expf(M - m) + s; M = m; }
            else { S += s * __expf(m - M); }
        }
        float logZ = M + __logf(S);
        int t = r >> 6, b = r & 63;
        int tg = ts[(t + 1) * NB + b];
        mk = (tg != 0) ? 1.f : 0.f;
        nll = (logZ - tgt[r]) * mk;
    }
#pragma unroll
    for (int m = 1; m < 64; m <<= 1) { nll += __shfl_xor(nll, m); mk += __shfl_xor(mk, m); }
    if ((threadIdx.x & 63) == 0) { atomicAdd(&sums[0], nll); atomicAdd(&sums[1], mk); }
}

__global__ void final_div(const float* __restrict__ sums, float* __restrict__ out) { out[0] = sums[0] / sums[1]; }

// ==================== host ====================
extern "C" void kernel_launch(void* const* d_in, const int* in_sizes, int n_in,
                              void* d_out, int out_size, void* d_ws, size_t ws_size,
                              hipStream_t stream) {
    const int* xs = (const int*)d_in[0];
    const int* ts = (const int*)d_in[1];
    const float* src_emb = (const float*)d_in[2];
    const float* tgt_emb = (const float*)d_in[3];
    const float* encf_Wih = (const float*)d_in[4];
    const float* encf_Whh = (const float*)d_in[5];
    const float* encf_bih = (const float*)d_in[6];
    const float* encf_bhh = (const float*)d_in[7];
    const float* encb_Wih = (const float*)d_in[8];
    const float* encb_Whh = (const float*)d_in[9];
    const float* encb_bih = (const float*)d_in[10];
    const float* encb_bhh = (const float*)d_in[11];
    const float* dec_Wih = (const float*)d_in[12];
    const float* dec_Whh = (const float*)d_in[13];
    const float* dec_bih = (const float*)d_in[14];
    const float* dec_bhh = (const float*)d_in[15];
    const float* attn_W = (const float*)d_in[16];
    const float* attn_v = (const float*)d_in[17];
    const float* lin_W = (const float*)d_in[18];
    const float* lin_b = (const float*)d_in[19];
    const float* out_W = (const float*)d_in[20];
    const float* out_b = (const float*)d_in[21];

    char* p = (char*)d_ws;
    auto alloc = [&](size_t bytes) { void* r = (void*)p; p += (bytes + 255) & ~(size_t)255; return r; };

    // zero zone (contiguous)
    float* hf0 = (float*)alloc(NB * 512 * 4);   // enc fwd h (s even in), + hb0 contiguous
    float* hb0 = (float*)alloc(NB * 512 * 4);
    float* hd0 = (float*)alloc(NB * 512 * 4);
    float* od = (float*)alloc(NB * 512 * 4);
    float* sums = (float*)alloc(2 * 4);
    const int ZN = 4 * NB * 512 + 64;

    float* hf1 = (float*)alloc(NB * 512 * 4);   // + hb1 contiguous
    float* hb1 = (float*)alloc(NB * 512 * 4);
    float* hd1 = (float*)alloc(NB * 512 * 4);
    float* wcomb = (float*)alloc((size_t)G * 1024 * 4);
    float* qbuf = (float*)alloc((size_t)NB * 1024 * 4);
    float* stats = (float*)alloc((size_t)NCB * MDEC * 2 * 4);
    float* tgtl = (float*)alloc((size_t)MDEC * 4);

    us* embs_bf = (us*)alloc((size_t)MENC * E * 2);
    us* tembs_bf = (us*)alloc((size_t)MDEC * E * 2);
    us* wfih_bf = (us*)alloc((size_t)G * 512 * 2);
    us* wbih_bf = (us*)alloc((size_t)G * 512 * 2);
    us* wdE_bf = (us*)alloc((size_t)G * 512 * 2);
    us* wk_bf = (us*)alloc((size_t)1024 * 1024 * 2);
    us* linw_bf = (us*)alloc((size_t)512 * 1536 * 2);
    us* wout_bf = (us*)alloc((size_t)V * 512 * 2);
    us* gxf_bf = (us*)alloc((size_t)MENC * G * 2);
    us* gxb_bf = (us*)alloc((size_t)MENC * G * 2);
    us* gemb_bf = (us*)alloc((size_t)MDEC * G * 2);
    us* hs_bf = (us*)alloc((size_t)MENC * 1024 * 2);
    us* hsproj_bf = (us*)alloc((size_t)MENC * 1024 * 2);
    us* hdec_bf = (us*)alloc((size_t)MDEC * 512 * 2);

    zero_k<<<dim3((ZN + 255) / 256), 256, 0, stream>>>(hf0, ZN);

    conv_bf16<<<dim3((G * 512 + 255) / 256), 256, 0, stream>>>(encf_Wih, 512, 0, wfih_bf, G, 512);
    conv_bf16<<<dim3((G * 512 + 255) / 256), 256, 0, stream>>>(encb_Wih, 512, 0, wbih_bf, G, 512);
    conv_bf16<<<dim3((G * 512 + 255) / 256), 256, 0, stream>>>(dec_Wih, 1024, 0, wdE_bf, G, 512);
    conv_bf16<<<dim3((1024 * 1024 + 255) / 256), 256, 0, stream>>>(attn_W, 1536, 512, wk_bf, 1024, 1024);
    conv_bf16<<<dim3((512 * 1536 + 255) / 256), 256, 0, stream>>>(lin_W, 1536, 0, linw_bf, 512, 1536);
    conv_bf16<<<dim3((V * 512 + 255) / 256), 256, 0, stream>>>(out_W, 512, 0, wout_bf, V, 512);
    pack_wcomb<<<dim3(G * 1024 / 256), 256, 0, stream>>>(dec_Wih, dec_Whh, wcomb);

    gather_bf16<<<dim3(MENC), 256, 0, stream>>>(xs, src_emb, embs_bf);
    gather_bf16<<<dim3(MDEC), 256, 0, stream>>>(ts, tgt_emb, tembs_bf);

    gemm16<1><<<dim3(G / 64, MENC / 64), 256, 0, stream>>>(embs_bf, 512, wfih_bf, 512, encf_bih, encf_bhh, gxf_bf, G, 512, 0);
    gemm16<1><<<dim3(G / 64, MENC / 64), 256, 0, stream>>>(embs_bf, 512, wbih_bf, 512, encb_bih, encb_bhh, gxb_bf, G, 512, 0);
    gemm16<1><<<dim3(G / 64, MDEC / 64), 256, 0, stream>>>(tembs_bf, 512, wdE_bf, 512, dec_bih, dec_bhh, gemb_bf, G, 512, 0);

    // persistent encoder
    {
        const us* a0 = gxf_bf; const us* a1 = gxb_bf;
        const float* a2 = encf_Whh; const float* a3 = encb_Whh;
        float* a4 = hf0; float* a5 = hf1;
        us* a6 = hs_bf;
        void* args[] = { &a0, &a1, &a2, &a3, &a4, &a5, &a6 };
        hipLaunchCooperativeKernel((void*)enc_coop, dim3(256), dim3(256), args, 0, stream);
    }

    gemm16<1><<<dim3(1024 / 64, MENC / 64), 256, 0, stream>>>(hs_bf, 1024, wk_bf, 1024, nullptr, nullptr, hsproj_bf, 1024, 1024, 0);

    // persistent decoder
    {
        const us* a0 = gemb_bf; const float* a1 = wcomb;
        const float* a2 = attn_W; const float* a3 = attn_v;
        const us* a4 = hsproj_bf; const us* a5 = hs_bf;
        const us* a6 = linw_bf; const float* a7 = lin_b;
        float* a8 = hd0; float* a9 = hd1;
        float* a10 = od; float* a11 = qbuf;
        us* a12 = hdec_bf;
        void* args[] = { &a0, &a1, &a2, &a3, &a4, &a5, &a6, &a7, &a8, &a9, &a10, &a11, &a12 };
        hipLaunchCooperativeKernel((void*)dec_coop, dim3(256), dim3(256), args, 0, stream);
    }

    gemm16<2><<<dim3(NCB, MDEC / 64), 256, 0, stream>>>(hdec_bf, 512, wout_bf, 512, out_b, nullptr, stats, 0, 512, MDEC);

    tgt_kernel<<<dim3(MDEC / 4), 256, 0, stream>>>(hdec_bf, wout_bf, out_b, ts, tgtl);
    stats_reduce<<<dim3((MDEC + 255) / 256), 256, 0, stream>>>(stats, tgtl, ts, sums);
    final_div<<<dim3(1), 1, 0, stream>>>(sums, (float*)d_out);
}